// Round 12
// baseline (72.770 us; speedup 1.0000x reference)
//
#include <hip/hip_runtime.h>
#include <hip/hip_fp16.h>

#define CDIM 512
#define ROWS 65536
#define TPW  16     // 32-row tiles per WG; 128 rowblocks x 16 x 32 = 65536

typedef _Float16 half8  __attribute__((ext_vector_type(8)));
typedef __fp16   fp16x2 __attribute__((ext_vector_type(2)));
typedef float    f32x16 __attribute__((ext_vector_type(16)));

__device__ __forceinline__ half8 cvt8(float4 f0, float4 f1) {
    union { fp16x2 h2[4]; half8 h8; } u;
    u.h2[0] = __builtin_amdgcn_cvt_pkrtz(f0.x, f0.y);
    u.h2[1] = __builtin_amdgcn_cvt_pkrtz(f0.z, f0.w);
    u.h2[2] = __builtin_amdgcn_cvt_pkrtz(f1.x, f1.y);
    u.h2[3] = __builtin_amdgcn_cvt_pkrtz(f1.z, f1.w);
    return u.h8;
}

// ---------------- K1 (fused): blocks 0..31 qproj, blocks 32..159 wkfrag ----------------
__global__ void prep_kernel(const float* __restrict__ Q, const float* __restrict__ Wq,
                            const float* __restrict__ bq, const float* __restrict__ Wout,
                            const float* __restrict__ Wk,
                            float* __restrict__ v, _Float16* __restrict__ Wkf) {
    __shared__ float qs[CDIM];
    const int t = threadIdx.x;
    if (blockIdx.x < 32) {
        // v[j] = relu(Q.Wq[j,:]+bq[j]) * Wout[j/64] / 8 ; bout dropped (softmax shift-invariant)
        qs[t] = Q[t]; qs[t + 256] = Q[t + 256];
        __syncthreads();
        const int jj  = t >> 4;
        const int sub = t & 15;
        const int j   = blockIdx.x * 16 + jj;
        const float4* w4 = (const float4*)(Wq + (size_t)j * CDIM + sub * 32);
        const float4* q4 = (const float4*)(qs + sub * 32);
        float s = 0.f;
        #pragma unroll
        for (int i = 0; i < 8; ++i) {
            float4 w = w4[i]; float4 q = q4[i];
            s = fmaf(w.x, q.x, s); s = fmaf(w.y, q.y, s);
            s = fmaf(w.z, q.z, s); s = fmaf(w.w, q.w, s);
        }
        s += __shfl_xor(s, 1); s += __shfl_xor(s, 2);
        s += __shfl_xor(s, 4); s += __shfl_xor(s, 8);
        if (sub == 0) {
            s += bq[j];
            s = fmaxf(s, 0.f);
            v[j] = s * Wout[j >> 6] * 0.125f;
        }
    } else {
        // Wk -> fp16 B-fragments [jb][kc][lane][8]; frag(jb,kc) lane l:
        // B[k=kc*16+(l>>5)*8+e][j=jb*32+(l&31)]
        const int gid = (blockIdx.x - 32) * 256 + t;
        const int jb  = gid >> 11;
        const int kc  = (gid >> 6) & 31;
        const int l   = gid & 63;
        const int j   = jb * 32 + (l & 31);
        const int k   = kc * 16 + (l >> 5) * 8;
        const float* src = Wk + (size_t)j * CDIM + k;
        float4 f0 = *(const float4*)(src);
        float4 f1 = *(const float4*)(src + 4);
        *(half8*)(Wkf + (size_t)gid * 8) = cvt8(f0, f1);
    }
}

// ---------------- K2: 64 j/wave (B0+B1 resident), 4-wave WG, full-tile-ahead prefetch ----
// 256 WGs = 128 rowblocks x 2 classes (partners bid,bid+8 share XCD). 1 WG/CU.
// Per 32-row tile: 32 ds_read_b128 feed 64 MFMAs. Prefetch: all 16 float4 for tile T+1
// issued at END of tile T-1 (cover = tree + barrier + full tile compute ~1800cy);
// written to LDS at end of tile T. Frag-major LDS: zero conflicts both sides.
__global__ __launch_bounds__(256, 1) void score_kernel(
    const float* __restrict__ Kmat, const _Float16* __restrict__ Wkf,
    const float* __restrict__ bk, const float* __restrict__ v,
    float* __restrict__ partial2)
{
    __shared__ alignas(16) char fragbuf[2][32768];   // 2 x (32 kc x 64 lanes x 16B)
    __shared__ float scratch2[2][4][32];

    const int tid  = threadIdx.x;
    const int lane = tid & 63;
    const int wave = tid >> 6;          // 0..3
    const int l31  = lane & 31;
    const int lhi  = lane >> 5;

    const int bid      = blockIdx.x;
    const int cls      = (bid >> 3) & 1;
    const int rowblock = (bid & 7) * 16 + (bid >> 4);   // partners bid, bid+8: same XCD
    const int rowbase  = rowblock * (TPW * 32);
    float* pbase = partial2 + (size_t)cls * ROWS;

    // ---- B prologue: two resident j-blocks (full depth) ----
    half8 B0[32], B1[32];
    {
        const half8* b0 = (const half8*)Wkf + (size_t)(cls * 8 + wave) * 2048 + lane;
        const half8* b1 = (const half8*)Wkf + (size_t)(cls * 8 + 4 + wave) * 2048 + lane;
        #pragma unroll
        for (int kc = 0; kc < 32; ++kc) { B0[kc] = b0[kc * 64]; B1[kc] = b1[kc * 64]; }
    }
    const int j0 = (cls * 8 + wave) * 32 + l31;
    const int j1 = (cls * 8 + 4 + wave) * 32 + l31;
    const float bj0 = bk[j0], vj0 = v[j0];
    const float bj1 = bk[j1], vj1 = v[j1];

    // staging: thread (lane, wave) owns 8 frags kc = q*8 + h*4 + wave (q=0..3, h=0..1)
    const int srow = lane & 31;
    const int skof = (lane >> 5) * 8;
    const float* gbase = Kmat + (size_t)(rowbase + srow) * CDIM + skof;

    // ---- prologue: stage tile 0 directly; issue all of tile 1 into L ----
    #pragma unroll
    for (int i = 0; i < 8; ++i) {
        const int kc = (i >> 1) * 8 + (i & 1) * 4 + wave;
        float4 f0 = *(const float4*)(gbase + kc * 16);
        float4 f1 = *(const float4*)(gbase + kc * 16 + 4);
        *(half8*)(&fragbuf[0][kc * 1024 + lane * 16]) = cvt8(f0, f1);
    }
    float4 L[8][2];
    #pragma unroll
    for (int i = 0; i < 8; ++i) {
        const int kc = (i >> 1) * 8 + (i & 1) * 4 + wave;
        L[i][0] = *(const float4*)(gbase + 32 * CDIM + kc * 16);
        L[i][1] = *(const float4*)(gbase + 32 * CDIM + kc * 16 + 4);
    }
    __syncthreads();

    for (int t = 0; t < TPW; ++t) {
        const int cur = t & 1;
        const char* sb = fragbuf[cur];
        char* db = fragbuf[cur ^ 1];

        // lagged cross-wave summer for tile t-1
        if (t > 0 && tid < 32) {
            const int pt = (t - 1) & 1;
            float s = scratch2[pt][0][tid] + scratch2[pt][1][tid]
                    + scratch2[pt][2][tid] + scratch2[pt][3][tid];
            pbase[rowbase + (t - 1) * 32 + tid] = s;
        }

        f32x16 acc0, acc1;
        #pragma unroll
        for (int r = 0; r < 16; ++r) { acc0[r] = 0.f; acc1[r] = 0.f; }

        // ---- compute: 32 frag reads, 64 MFMAs (each read feeds both j-blocks) ----
        #pragma unroll
        for (int kc = 0; kc < 32; kc += 2) {
            half8 a0 = *(const half8*)(sb + kc * 1024 + lane * 16);
            half8 a1 = *(const half8*)(sb + (kc + 1) * 1024 + lane * 16);
            acc0 = __builtin_amdgcn_mfma_f32_32x32x16_f16(a0, B0[kc], acc0, 0, 0, 0);
            acc1 = __builtin_amdgcn_mfma_f32_32x32x16_f16(a0, B1[kc], acc1, 0, 0, 0);
            acc0 = __builtin_amdgcn_mfma_f32_32x32x16_f16(a1, B0[kc + 1], acc0, 0, 0, 0);
            acc1 = __builtin_amdgcn_mfma_f32_32x32x16_f16(a1, B1[kc + 1], acc1, 0, 0, 0);
        }
        __builtin_amdgcn_sched_barrier(0);

        // ---- write tile t+1 (loaded a full tile ago); then issue tile t+2 ----
        if (t + 1 < TPW) {
            #pragma unroll
            for (int i = 0; i < 8; ++i) {
                const int kc = (i >> 1) * 8 + (i & 1) * 4 + wave;
                *(half8*)(db + kc * 1024 + lane * 16) = cvt8(L[i][0], L[i][1]);
            }
        }
        if (t + 2 < TPW) {
            const float* gt = gbase + (size_t)(t + 2) * 32 * CDIM;
            #pragma unroll
            for (int i = 0; i < 8; ++i) {
                const int kc = (i >> 1) * 8 + (i & 1) * 4 + wave;
                L[i][0] = *(const float4*)(gt + kc * 16);
                L[i][1] = *(const float4*)(gt + kc * 16 + 4);
            }
        }
        __builtin_amdgcn_sched_barrier(0);

        // ---- epilogue: relu + v-weight (both j-blocks), fold-tree over 32 j-lanes ----
        {
            float part[16];
            #pragma unroll
            for (int r = 0; r < 16; ++r)
                part[r] = fmaxf(acc0[r] + bj0, 0.f) * vj0 + fmaxf(acc1[r] + bj1, 0.f) * vj1;

            float q0[8];
            #pragma unroll
            for (int i = 0; i < 8; ++i) {
                const bool b = lane & 1;
                float keep = b ? part[i + 8] : part[i];
                float send = b ? part[i] : part[i + 8];
                q0[i] = keep + __shfl_xor(send, 1);
            }
            float q1[4];
            #pragma unroll
            for (int i = 0; i < 4; ++i) {
                const bool b = lane & 2;
                float keep = b ? q0[i + 4] : q0[i];
                float send = b ? q0[i] : q0[i + 4];
                q1[i] = keep + __shfl_xor(send, 2);
            }
            float q2[2];
            #pragma unroll
            for (int i = 0; i < 2; ++i) {
                const bool b = lane & 4;
                float keep = b ? q1[i + 2] : q1[i];
                float send = b ? q1[i] : q1[i + 2];
                q2[i] = keep + __shfl_xor(send, 4);
            }
            float q3;
            {
                const bool b = lane & 8;
                float keep = b ? q2[1] : q2[0];
                float send = b ? q2[0] : q2[1];
                q3 = keep + __shfl_xor(send, 8);
            }
            float s = q3 + __shfl_xor(q3, 16);
            if (l31 < 16) {
                const int rr  = ((l31 & 1) << 3) | ((l31 & 2) << 1) | ((l31 & 4) >> 1) | ((l31 & 8) >> 3);
                const int row = (rr & 3) + 8 * (rr >> 2) + 4 * lhi;
                scratch2[cur][wave][row] = s;
            }
        }

        __syncthreads();
    }

    // drain: summer for the last tile
    if (tid < 32) {
        const int pt = (TPW - 1) & 1;
        float s = scratch2[pt][0][tid] + scratch2[pt][1][tid]
                + scratch2[pt][2][tid] + scratch2[pt][3][tid];
        pbase[rowbase + (TPW - 1) * 32 + tid] = s;
    }
}

// ---------------- K3: merge 2 classes, store logits, per-block exp-sum ----------------
__global__ void expsum_kernel(const float* __restrict__ partial2, float* __restrict__ logits,
                              float* __restrict__ blocksum) {
    __shared__ float red[256];
    const int t = threadIdx.x;
    const int row = blockIdx.x * 256 + t;
    const float lg = partial2[row] + partial2[ROWS + row];
    logits[row] = lg;
    red[t] = expf(lg);
    __syncthreads();
    for (int s = 128; s > 0; s >>= 1) {
        if (t < s) red[t] += red[t + s];
        __syncthreads();
    }
    if (t == 0) blocksum[blockIdx.x] = red[0];
}

// ---------------- K4: normalize ----------------
__global__ void norm_kernel(const float* __restrict__ logits, const float* __restrict__ blocksum,
                            float* __restrict__ out) {
    __shared__ float red[256];
    const int t = threadIdx.x;
    red[t] = blocksum[t];
    __syncthreads();
    for (int s = 128; s > 0; s >>= 1) {
        if (t < s) red[t] += red[t + s];
        __syncthreads();
    }
    const float zinv = 1.0f / red[0];
    const int i = blockIdx.x * 256 + t;
    out[i] = expf(logits[i]) * zinv;
}

extern "C" void kernel_launch(void* const* d_in, const int* in_sizes, int n_in,
                              void* d_out, int out_size, void* d_ws, size_t ws_size,
                              hipStream_t stream) {
    const float* Q    = (const float*)d_in[0];
    const float* Kmat = (const float*)d_in[1];
    const float* Wq   = (const float*)d_in[2];
    const float* bq   = (const float*)d_in[3];
    const float* Wk   = (const float*)d_in[4];
    const float* bk   = (const float*)d_in[5];
    const float* Wout = (const float*)d_in[6];
    float* out = (float*)d_out;

    char* ws = (char*)d_ws;
    _Float16* Wkf   = (_Float16*)(ws);                // 524288 B
    float* v        = (float*)(ws + 524288);          //   2048 B
    float* partial2 = (float*)(ws + 526336);          // 524288 B (2 classes x 65536)
    float* logits   = (float*)(ws + 1050624);         // 262144 B
    float* blocksum = (float*)(ws + 1312768);         //   1024 B

    hipLaunchKernelGGL(prep_kernel,   dim3(160),  dim3(256), 0, stream, Q, Wq, bq, Wout, Wk, v, Wkf);
    hipLaunchKernelGGL(score_kernel,  dim3(256),  dim3(256), 0, stream, Kmat, Wkf, bk, v, partial2);
    hipLaunchKernelGGL(expsum_kernel, dim3(256),  dim3(256), 0, stream, partial2, logits, blocksum);
    hipLaunchKernelGGL(norm_kernel,   dim3(256),  dim3(256), 0, stream, logits, blocksum, out);
}

// Round 13
// 62.428 us; speedup vs baseline: 1.1657x; 1.1657x over previous
//
#include <hip/hip_runtime.h>
#include <hip/hip_fp16.h>

#define CDIM 512
#define ROWS 65536

typedef _Float16 half8  __attribute__((ext_vector_type(8)));
typedef __fp16   fp16x2 __attribute__((ext_vector_type(2)));
typedef float    f32x16 __attribute__((ext_vector_type(16)));

// async global->LDS, 16B per lane; LDS dest = wave-uniform base + lane*16
#define GLD_LDS16(gp, lp) __builtin_amdgcn_global_load_lds( \
    (const __attribute__((address_space(1))) unsigned int*)(gp), \
    (__attribute__((address_space(3))) unsigned int*)(lp), 16, 0, 0)

__device__ __forceinline__ half8 cvt8(float4 f0, float4 f1) {
    union { fp16x2 h2[4]; half8 h8; } u;
    u.h2[0] = __builtin_amdgcn_cvt_pkrtz(f0.x, f0.y);
    u.h2[1] = __builtin_amdgcn_cvt_pkrtz(f0.z, f0.w);
    u.h2[2] = __builtin_amdgcn_cvt_pkrtz(f1.x, f1.y);
    u.h2[3] = __builtin_amdgcn_cvt_pkrtz(f1.z, f1.w);
    return u.h8;
}

// ---------------- K1 (fused): blocks 0..31 qproj, blocks 32..159 wkfrag ----------------
__global__ void prep_kernel(const float* __restrict__ Q, const float* __restrict__ Wq,
                            const float* __restrict__ bq, const float* __restrict__ Wout,
                            const float* __restrict__ Wk,
                            float* __restrict__ v, _Float16* __restrict__ Wkf) {
    __shared__ float qs[CDIM];
    const int t = threadIdx.x;
    if (blockIdx.x < 32) {
        // v[j] = relu(Q.Wq[j,:]+bq[j]) * Wout[j/64] / 8 ; bout dropped (softmax shift-invariant)
        qs[t] = Q[t]; qs[t + 256] = Q[t + 256];
        __syncthreads();
        const int jj  = t >> 4;
        const int sub = t & 15;
        const int j   = blockIdx.x * 16 + jj;
        const float4* w4 = (const float4*)(Wq + (size_t)j * CDIM + sub * 32);
        const float4* q4 = (const float4*)(qs + sub * 32);
        float s = 0.f;
        #pragma unroll
        for (int i = 0; i < 8; ++i) {
            float4 w = w4[i]; float4 q = q4[i];
            s = fmaf(w.x, q.x, s); s = fmaf(w.y, q.y, s);
            s = fmaf(w.z, q.z, s); s = fmaf(w.w, q.w, s);
        }
        s += __shfl_xor(s, 1); s += __shfl_xor(s, 2);
        s += __shfl_xor(s, 4); s += __shfl_xor(s, 8);
        if (sub == 0) {
            s += bq[j];
            s = fmaxf(s, 0.f);
            v[j] = s * Wout[j >> 6] * 0.125f;
        }
    } else {
        // Wk -> fp16 B-fragments [jb 0..15][kc 0..31][lane 0..63][8 halfs]
        // frag(jb,kc) lane l: B[k=kc*16+(l>>5)*8+e][j=jb*32+(l&31)]
        const int gid = (blockIdx.x - 32) * 256 + t;
        const int jb  = gid >> 11;
        const int kc  = (gid >> 6) & 31;
        const int l   = gid & 63;
        const int j   = jb * 32 + (l & 31);
        const int k   = kc * 16 + (l >> 5) * 8;
        const float* src = Wk + (size_t)j * CDIM + k;
        float4 f0 = *(const float4*)(src);
        float4 f1 = *(const float4*)(src + 4);
        *(half8*)(Wkf + (size_t)gid * 8) = cvt8(f0, f1);
    }
}

// ---------------- K2: A-in-regs full-K (32 rows/wave), B 64j-chunks via DMA LDS ----------
// 256 WGs x 512 thr (8 waves). Wave w owns rows bid*256 + w*32 .. +31 -- full K in a[32].
// K read ONCE per CU (512KB). All 512 j per wave: 8 chunks x 64 j, dbuf 2x64KB,
// chunk c+1 DMA'd (global_load_lds, linear, conflict-free) while c computes.
// part[] accumulates relu(acc+b)*v across chunks; ONE fold-tree at the end.
__global__ __launch_bounds__(512, 1) void score_kernel(
    const float* __restrict__ Kmat, const _Float16* __restrict__ Wkf,
    const float* __restrict__ bk, const float* __restrict__ v,
    float* __restrict__ logits)
{
    __shared__ alignas(16) char Bb[2][65536];   // 2 x (2 jb x 32 kc x 64 lanes x 16B)

    const int tid  = threadIdx.x;
    const int lane = tid & 63;
    const int wave = tid >> 6;          // 0..7
    const int l31  = lane & 31;
    const int lhi  = lane >> 5;
    const int rowbase = blockIdx.x * 256;

    // ---- issue chunk-0 DMA first (overlaps the A prologue) ----
    #pragma unroll
    for (int i = 0; i < 8; ++i)
        GLD_LDS16((const char*)Wkf + i * 8192 + tid * 16, Bb[0] + i * 8192 + tid * 16);

    // ---- A prologue: this wave's 32 rows, full K=512, fp32->fp16 fragments ----
    half8 a[32];
    {
        const float* ab = Kmat + (size_t)(rowbase + wave * 32 + l31) * CDIM + lhi * 8;
        #pragma unroll
        for (int kc = 0; kc < 32; ++kc) {
            float4 f0 = *(const float4*)(ab + kc * 16);
            float4 f1 = *(const float4*)(ab + kc * 16 + 4);
            a[kc] = cvt8(f0, f1);
        }
    }

    float part[16];
    #pragma unroll
    for (int r = 0; r < 16; ++r) part[r] = 0.f;

    __syncthreads();   // chunk 0 landed

    for (int c = 0; c < 8; ++c) {
        const int cur = c & 1;

        // DMA chunk c+1 into the other buffer (in flight across this chunk's compute)
        if (c < 7) {
            const char* src = (const char*)Wkf + (size_t)(c + 1) * 65536;
            #pragma unroll
            for (int i = 0; i < 8; ++i)
                GLD_LDS16(src + i * 8192 + tid * 16, Bb[cur ^ 1] + i * 8192 + tid * 16);
        }

        const int jg0 = c * 64 + l31;
        const float bj0 = bk[jg0],      vj0 = v[jg0];
        const float bj1 = bk[jg0 + 32], vj1 = v[jg0 + 32];

        f32x16 acc0, acc1;
        #pragma unroll
        for (int r = 0; r < 16; ++r) { acc0[r] = 0.f; acc1[r] = 0.f; }

        // 64 conflict-free ds_read_b128 feed 64 MFMAs (A reused from regs)
        #pragma unroll
        for (int kc = 0; kc < 32; ++kc) {
            half8 b0 = *(const half8*)(Bb[cur] + kc * 1024 + lane * 16);
            half8 b1 = *(const half8*)(Bb[cur] + (32 + kc) * 1024 + lane * 16);
            acc0 = __builtin_amdgcn_mfma_f32_32x32x16_f16(a[kc], b0, acc0, 0, 0, 0);
            acc1 = __builtin_amdgcn_mfma_f32_32x32x16_f16(a[kc], b1, acc1, 0, 0, 0);
        }

        #pragma unroll
        for (int r = 0; r < 16; ++r)
            part[r] += fmaxf(acc0[r] + bj0, 0.f) * vj0 + fmaxf(acc1[r] + bj1, 0.f) * vj1;

        __syncthreads();   // drains DMA (vmcnt) + all reads before buffer swap
    }

    // ---- epilogue (once): fold-tree over the 32 j-lanes; write this wave's 32 rows ----
    {
        float q0[8];
        #pragma unroll
        for (int i = 0; i < 8; ++i) {
            const bool b = lane & 1;
            float keep = b ? part[i + 8] : part[i];
            float send = b ? part[i] : part[i + 8];
            q0[i] = keep + __shfl_xor(send, 1);
        }
        float q1[4];
        #pragma unroll
        for (int i = 0; i < 4; ++i) {
            const bool b = lane & 2;
            float keep = b ? q0[i + 4] : q0[i];
            float send = b ? q0[i] : q0[i + 4];
            q1[i] = keep + __shfl_xor(send, 2);
        }
        float q2[2];
        #pragma unroll
        for (int i = 0; i < 2; ++i) {
            const bool b = lane & 4;
            float keep = b ? q1[i + 2] : q1[i];
            float send = b ? q1[i] : q1[i + 2];
            q2[i] = keep + __shfl_xor(send, 4);
        }
        float q3;
        {
            const bool b = lane & 8;
            float keep = b ? q2[1] : q2[0];
            float send = b ? q2[0] : q2[1];
            q3 = keep + __shfl_xor(send, 8);
        }
        float s = q3 + __shfl_xor(q3, 16);
        if (l31 < 16) {
            const int rr  = ((l31 & 1) << 3) | ((l31 & 2) << 1) | ((l31 & 4) >> 1) | ((l31 & 8) >> 3);
            const int row = (rr & 3) + 8 * (rr >> 2) + 4 * lhi;
            logits[rowbase + wave * 32 + row] = s;
        }
    }
}

// ---------------- K3: per-block exp-sum over logits ----------------
__global__ void expsum_kernel(const float* __restrict__ logits, float* __restrict__ blocksum) {
    __shared__ float red[256];
    const int t = threadIdx.x;
    red[t] = expf(logits[blockIdx.x * 256 + t]);
    __syncthreads();
    for (int s = 128; s > 0; s >>= 1) {
        if (t < s) red[t] += red[t + s];
        __syncthreads();
    }
    if (t == 0) blocksum[blockIdx.x] = red[0];
}

// ---------------- K4: normalize ----------------
__global__ void norm_kernel(const float* __restrict__ logits, const float* __restrict__ blocksum,
                            float* __restrict__ out) {
    __shared__ float red[256];
    const int t = threadIdx.x;
    red[t] = blocksum[t];
    __syncthreads();
    for (int s = 128; s > 0; s >>= 1) {
        if (t < s) red[t] += red[t + s];
        __syncthreads();
    }
    const float zinv = 1.0f / red[0];
    const int i = blockIdx.x * 256 + t;
    out[i] = expf(logits[i]) * zinv;
}

extern "C" void kernel_launch(void* const* d_in, const int* in_sizes, int n_in,
                              void* d_out, int out_size, void* d_ws, size_t ws_size,
                              hipStream_t stream) {
    const float* Q    = (const float*)d_in[0];
    const float* Kmat = (const float*)d_in[1];
    const float* Wq   = (const float*)d_in[2];
    const float* bq   = (const float*)d_in[3];
    const float* Wk   = (const float*)d_in[4];
    const float* bk   = (const float*)d_in[5];
    const float* Wout = (const float*)d_in[6];
    float* out = (float*)d_out;

    char* ws = (char*)d_ws;
    _Float16* Wkf   = (_Float16*)(ws);                // 524288 B
    float* v        = (float*)(ws + 524288);          //   2048 B
    float* logits   = (float*)(ws + 526336);          // 262144 B
    float* blocksum = (float*)(ws + 788480);          //   1024 B

    hipLaunchKernelGGL(prep_kernel,   dim3(160),  dim3(256), 0, stream, Q, Wq, bq, Wout, Wk, v, Wkf);
    hipLaunchKernelGGL(score_kernel,  dim3(256),  dim3(512), 0, stream, Kmat, Wkf, bk, v, logits);
    hipLaunchKernelGGL(expsum_kernel, dim3(256),  dim3(256), 0, stream, logits, blocksum);
    hipLaunchKernelGGL(norm_kernel,   dim3(256),  dim3(256), 0, stream, logits, blocksum, out);
}